// Round 5
// baseline (318.442 us; speedup 1.0000x reference)
//
#include <hip/hip_runtime.h>
#include <hip/hip_bf16.h>
#include <math.h>

// Sizes (fixed by the problem)
#define BATCH 16
#define TLEN  512
#define HD    16     // per-direction hidden
#define HID   32     // 2*HD

// Static device scratch — avoids any assumption about ws_size.
// All arrays fully written before read on every call; g_cnt is zero-init
// .bss and restored to 0 by the last-arriver block each call.
__device__ float g_outBT[BATCH * TLEN * HID];   // 1 MB
__device__ float g_preA [BATCH * TLEN * HID];   // 1 MB
__device__ float g_Ct   [BATCH * HID * TLEN];   // 1 MB
__device__ float g_un   [BATCH * TLEN];
__device__ float g_w2d  [BATCH * TLEN];
__device__ float g_part [BATCH][64];
__device__ int   g_cnt  [BATCH];                // zero-initialized

__device__ __forceinline__ float sigm_(float x) {
    return 1.0f / (1.0f + __expf(-x));
}
__device__ __forceinline__ float tanh_(float x) {
    float e = __expf(2.0f * x);
    return 1.0f - 2.0f / (e + 1.0f);
}

__device__ __forceinline__ float dot16(const float* w, const float* h, float init) {
    float d0 = fmaf(w[0],  h[0],  fmaf(w[1],  h[1],  fmaf(w[2],  h[2],  w[3]  * h[3])));
    float d1 = fmaf(w[4],  h[4],  fmaf(w[5],  h[5],  fmaf(w[6],  h[6],  w[7]  * h[7])));
    float d2 = fmaf(w[8],  h[8],  fmaf(w[9],  h[9],  fmaf(w[10], h[10], w[11] * h[11])));
    float d3 = fmaf(w[12], h[12], fmaf(w[13], h[13], fmaf(w[14], h[14], w[15] * h[15])));
    return init + ((d0 + d1) + (d2 + d3));
}

// 16-element allgather within each 16-lane group via ds_swizzle (BitMode:
// src = (lane & 0x10) | K within each 32-lane group; q-groups align at 0/16/32/48).
// Template recursion keeps the pattern a compile-time constant.
template <int K>
__device__ __forceinline__ void allgather16(float (&hr)[16], int hni) {
    hr[K] = __int_as_float(__builtin_amdgcn_ds_swizzle(hni, (K << 5) | 0x10));
    if constexpr (K < 15) allgather16<K + 1>(hr, hni);
}

// ---------------------------------------------------------------------------
// K1: bidirectional LSTM. 8 blocks x 64 threads; each wave carries 4 chains.
// Lane = (q = batch slot [0,4), u = unit [0,16)). Each lane computes ALL FOUR
// gate pre-activations for its unit in-lane (no gate-gather stage), applies
// activations + c/h update in-lane, then ONE cross-lane stage: 16 ds_swizzle
// broadcasts rebuild the full 16-vector h in every lane of the 16-lane group.
// ---------------------------------------------------------------------------
__global__ __launch_bounds__(64) void k1_lstm(
    const float* __restrict__ sent,   // [B,T]
    const float* __restrict__ h0,     // [2,B,16]
    const float* __restrict__ c0,     // [2,B,16]
    const float* __restrict__ Wih_f, const float* __restrict__ Whh_f, const float* __restrict__ b_f,
    const float* __restrict__ Wih_b, const float* __restrict__ Whh_b, const float* __restrict__ b_b)
{
    const int blk  = blockIdx.x;      // 0..7
    const int dir  = blk >> 2;        // 0 fwd, 1 bwd
    const int bg   = blk & 3;         // batch group of 4
    const int lane = threadIdx.x;
    const int q    = lane >> 4;       // batch slot in wave
    const int u    = lane & 15;       // hidden unit
    const int b    = bg * 4 + q;

    const float* Wih  = dir ? Wih_b : Wih_f;
    const float* Whh  = dir ? Whh_b : Whh_f;
    const float* bias = dir ? b_b   : b_f;

    // all 4 gate rows for unit u (torch order i,f,g,o at u, u+16, u+32, u+48)
    float wI[16], wF[16], wG[16], wO[16];
    #pragma unroll
    for (int k = 0; k < 16; ++k) {
        wI[k] = Whh[(u)      * 16 + k];
        wF[k] = Whh[(u + 16) * 16 + k];
        wG[k] = Whh[(u + 32) * 16 + k];
        wO[k] = Whh[(u + 48) * 16 + k];
    }
    const float wxI = Wih[u], wxF = Wih[u + 16], wxG = Wih[u + 32], wxO = Wih[u + 48];
    const float bI = bias[u], bF = bias[u + 16], bG = bias[u + 32], bO = bias[u + 48];

    float hr[16];
    #pragma unroll
    for (int k = 0; k < 16; ++k) hr[k] = h0[dir * (BATCH * HD) + b * HD + k];
    float c = c0[dir * (BATCH * HD) + b * HD + u];

    const float* srow = sent + b * TLEN;
    float* obase = g_outBT + (size_t)b * TLEN * HID + dir * HD + u;

    // double-buffered x chunk (4 steps per chunk); bwd consumes reversed
    float4 xc = *(const float4*)(srow + (dir ? (TLEN - 4) : 0));
    for (int tb = 0; tb < TLEN; tb += 4) {
        float4 xn = xc;
        if (tb + 4 < TLEN)
            xn = *(const float4*)(srow + (dir ? (TLEN - 8 - tb) : (tb + 4)));
        float xa[4];
        if (dir) { xa[0] = xc.w; xa[1] = xc.z; xa[2] = xc.y; xa[3] = xc.x; }
        else     { xa[0] = xc.x; xa[1] = xc.y; xa[2] = xc.z; xa[3] = xc.w; }

        #pragma unroll
        for (int s2 = 0; s2 < 4; ++s2) {
            const int t   = tb + s2;
            const int pos = dir ? (TLEN - 1 - t) : t;
            const float x = xa[s2];

            float pi = dot16(wI, hr, fmaf(x, wxI, bI));
            float pf = dot16(wF, hr, fmaf(x, wxF, bF));
            float pg = dot16(wG, hr, fmaf(x, wxG, bG));
            float po = dot16(wO, hr, fmaf(x, wxO, bO));

            float ai = sigm_(pi), af = sigm_(pf), ao = sigm_(po);
            float ag = tanh_(pg);
            c = fmaf(af, c, ai * ag);
            float hn = ao * tanh_(c);

            obase[(size_t)pos * HID] = hn;

            allgather16<0>(hr, __float_as_int(hn));
        }
        xc = xn;
    }
}

// ---------------------------------------------------------------------------
// K2: projections. Thread per (b,t). W1 etc. staged in LDS.
//   preA[b][t][h] = out[b,t,:] . W1[h,0:32]  + b1[h]
//   Ct  [b][h][t] = out[b,t,:] . W1[h,32:64]           (transposed for K34)
//   un  [b][t]    = out . Wu + bu
//   w2d [b][t]    = out . Wout
// ---------------------------------------------------------------------------
__global__ __launch_bounds__(256) void k2_proj(
    const float* __restrict__ W1,     // [32,64]
    const float* __restrict__ b1,     // [32]
    const float* __restrict__ Wu,     // [32]
    const float* __restrict__ bu,     // [1]
    const float* __restrict__ Wout)   // [32]
{
    __shared__ float w1s[HID * 64];
    __shared__ float b1s[HID], wus[HID], wos[HID];
    const int tid = threadIdx.x;
    for (int k = tid; k < HID * 64; k += 256) w1s[k] = W1[k];
    if (tid < HID) { b1s[tid] = b1[tid]; wus[tid] = Wu[tid]; wos[tid] = Wout[tid]; }
    __syncthreads();

    const int g = blockIdx.x * 256 + tid;    // 0..8191
    const int b = g >> 9;
    const int t = g & (TLEN - 1);

    float o[32];
    const float4* src = (const float4*)(g_outBT + (size_t)g * HID);
    #pragma unroll
    for (int qq = 0; qq < 8; ++qq) {
        float4 v = src[qq];
        o[qq * 4 + 0] = v.x; o[qq * 4 + 1] = v.y; o[qq * 4 + 2] = v.z; o[qq * 4 + 3] = v.w;
    }

    float* pa = g_preA + (size_t)g * HID;
    float* ct = g_Ct + (size_t)b * HID * TLEN + t;
    #pragma unroll 4
    for (int h = 0; h < HID; ++h) {
        float a = b1s[h], cacc = 0.f;
        const float* wr = &w1s[h * 64];
        #pragma unroll
        for (int k = 0; k < HID; ++k) {
            a    = fmaf(o[k], wr[k], a);
            cacc = fmaf(o[k], wr[32 + k], cacc);
        }
        pa[h] = a;
        ct[(size_t)h * TLEN] = cacc;
    }

    float ua = 0.f, wa = 0.f;
    #pragma unroll
    for (int k = 0; k < HID; ++k) { ua = fmaf(o[k], wus[k], ua); wa = fmaf(o[k], wos[k], wa); }
    g_un[g]  = ua + bu[0];
    g_w2d[g] = wa;
}

// ---------------------------------------------------------------------------
// K34: S[b,i] = sum_j sum_h relu(preA[b,i,h] + Ct[b,h,j]) * W2[h]
//      prob[b,i] = sigmoid((S - diag_i + 511*b2)/100 + un[b,i])
//      out[b] = sum_i prob[b,i]*w2d[b,i] / 512 + bout   (fused via semaphore)
// Block = (b, tile of 8 i's); 256 threads over j. Last-arriver block per b
// reduces the 64 per-tile partials and writes out[b], then resets the counter.
// ---------------------------------------------------------------------------
__global__ __launch_bounds__(256) void k34_binary(
    const float* __restrict__ W2,     // [32]
    const float* __restrict__ b2p,    // [1]
    const float* __restrict__ boutp,  // [1]
    float* __restrict__ out)          // [16]
{
    const int b     = blockIdx.x >> 6;
    const int itile = blockIdx.x & 63;
    const int i0    = itile * 8;
    const int tid   = threadIdx.x;

    __shared__ float pa[8][HID];
    __shared__ float w2s[HID];
    __shared__ float redw[4][8];

    pa[tid >> 5][tid & 31] = g_preA[((size_t)b * TLEN + i0 + (tid >> 5)) * HID + (tid & 31)];
    if (tid < HID) w2s[tid] = W2[tid];
    __syncthreads();

    const float* ctb = g_Ct + (size_t)b * HID * TLEN;
    const int j0 = tid, j1 = tid + 256;

    float acc[8];
    #pragma unroll
    for (int ii = 0; ii < 8; ++ii) acc[ii] = 0.f;

    for (int h = 0; h < HID; ++h) {
        const float c0v = ctb[(size_t)h * TLEN + j0];
        const float c1v = ctb[(size_t)h * TLEN + j1];
        const float w   = w2s[h];
        #pragma unroll
        for (int ii = 0; ii < 8; ++ii) {
            const float p = pa[ii][h];
            acc[ii] = fmaf(fmaxf(p + c0v, 0.f), w, acc[ii]);
            acc[ii] = fmaf(fmaxf(p + c1v, 0.f), w, acc[ii]);
        }
    }

    #pragma unroll
    for (int ii = 0; ii < 8; ++ii) {
        float v = acc[ii];
        #pragma unroll
        for (int off = 32; off >= 1; off >>= 1) v += __shfl_down(v, off);
        if ((tid & 63) == 0) redw[tid >> 6][ii] = v;
    }
    __syncthreads();

    if (tid < 8) {
        const float S = redw[0][tid] + redw[1][tid] + redw[2][tid] + redw[3][tid];
        const int i = i0 + tid;
        float diag = 0.f;
        #pragma unroll
        for (int h = 0; h < HID; ++h)
            diag = fmaf(fmaxf(pa[tid][h] + ctb[(size_t)h * TLEN + i], 0.f), w2s[h], diag);
        const float b2 = b2p[0];
        const float s = (S - diag + (float)(TLEN - 1) * b2) * 0.01f + g_un[(size_t)b * TLEN + i];
        float contrib = sigm_(s) * g_w2d[(size_t)b * TLEN + i];
        // reduce 8 lanes (lanes 0..7 of wave 0)
        contrib += __shfl_down(contrib, 4);
        contrib += __shfl_down(contrib, 2);
        contrib += __shfl_down(contrib, 1);
        if (tid == 0) {
            atomicExch(&g_part[b][itile], contrib);   // device-scope, coherent
            __threadfence();
            int old = atomicAdd(&g_cnt[b], 1);
            if (old == 63) {                          // last arriver for this b
                __threadfence();
                float tot = 0.f;
                for (int k = 0; k < 64; ++k)
                    tot += atomicAdd(&g_part[b][k], 0.0f);  // coherent read
                out[b] = tot * (1.0f / (float)TLEN) + boutp[0];
                atomicExch(&g_cnt[b], 0);             // restore for next call
            }
        }
    }
}

extern "C" void kernel_launch(void* const* d_in, const int* in_sizes, int n_in,
                              void* d_out, int out_size, void* d_ws, size_t ws_size,
                              hipStream_t stream) {
    const float* sent  = (const float*)d_in[0];
    const float* h0    = (const float*)d_in[1];
    const float* c0    = (const float*)d_in[2];
    const float* Wih_f = (const float*)d_in[3];
    const float* Whh_f = (const float*)d_in[4];
    const float* b_f   = (const float*)d_in[5];
    const float* Wih_b = (const float*)d_in[6];
    const float* Whh_b = (const float*)d_in[7];
    const float* b_b   = (const float*)d_in[8];
    const float* W1    = (const float*)d_in[9];
    const float* b1    = (const float*)d_in[10];
    const float* W2    = (const float*)d_in[11];
    const float* b2    = (const float*)d_in[12];
    const float* Wu    = (const float*)d_in[13];
    const float* bu    = (const float*)d_in[14];
    const float* Wout  = (const float*)d_in[15];
    const float* bout  = (const float*)d_in[16];

    k1_lstm<<<8, 64, 0, stream>>>(sent, h0, c0, Wih_f, Whh_f, b_f,
                                  Wih_b, Whh_b, b_b);
    k2_proj<<<32, 256, 0, stream>>>(W1, b1, Wu, bu, Wout);
    k34_binary<<<1024, 256, 0, stream>>>(W2, b2, bout, (float*)d_out);
}

// Round 6
// 308.294 us; speedup vs baseline: 1.0329x; 1.0329x over previous
//
#include <hip/hip_runtime.h>
#include <hip/hip_bf16.h>
#include <math.h>

// Sizes (fixed by the problem)
#define BATCH 16
#define TLEN  512
#define HD    16     // per-direction hidden
#define HID   32     // 2*HD

// Static device scratch — avoids any assumption about ws_size.
// All arrays fully written before read each call; g_cnt/g_accum are zero-init
// .bss and restored to 0 by the last-arriver block each call.
__device__ float g_outBT[BATCH * TLEN * HID];   // 1 MB
__device__ float g_preA [BATCH * TLEN * HID];   // 1 MB
__device__ float g_Ct   [BATCH * HID * TLEN];   // 1 MB
__device__ float g_un   [BATCH * TLEN];
__device__ float g_w2d  [BATCH * TLEN];
__device__ float g_accum[BATCH];                // zero-initialized, self-resetting
__device__ int   g_cnt  [BATCH];                // zero-initialized, self-resetting

__device__ __forceinline__ float sigm_(float x) {
    return 1.0f / (1.0f + __expf(-x));
}
__device__ __forceinline__ float tanh_(float x) {
    float e = __expf(2.0f * x);
    return 1.0f - 2.0f / (e + 1.0f);
}

// ---------------------------------------------------------------------------
// K1: bidirectional LSTM. 8 blocks x 64 threads; each wave carries 4 chains.
// Lane = (q = batch slot, u = unit). Recurrent h-distribution is fused into
// the gate dot-products via a DPP row_ror:1 rotation chain (16-lane rows =
// unit groups): cur_k on lane u holds h[(u-k)&15], and weights are loaded
// pre-rotated so w'[k] pairs with it. No LDS/DS ops in the loop at all.
// ---------------------------------------------------------------------------
__global__ __launch_bounds__(64) void k1_lstm(
    const float* __restrict__ sent,   // [B,T]
    const float* __restrict__ h0,     // [2,B,16]
    const float* __restrict__ c0,     // [2,B,16]
    const float* __restrict__ Wih_f, const float* __restrict__ Whh_f, const float* __restrict__ b_f,
    const float* __restrict__ Wih_b, const float* __restrict__ Whh_b, const float* __restrict__ b_b)
{
    const int blk  = blockIdx.x;      // 0..7
    const int dir  = blk >> 2;        // 0 fwd, 1 bwd
    const int bg   = blk & 3;         // batch group of 4
    const int lane = threadIdx.x;
    const int q    = lane >> 4;       // batch slot in wave
    const int u    = lane & 15;       // hidden unit
    const int b    = bg * 4 + q;

    const float* Wih  = dir ? Wih_b : Wih_f;
    const float* Whh  = dir ? Whh_b : Whh_f;
    const float* bias = dir ? b_b   : b_f;

    // Pre-rotated gate rows for unit u (torch order i,f,g,o at u,+16,+32,+48):
    // w*[k] multiplies h[(u-k)&15] (the value arriving after k row_ror:1 steps).
    float wI[16], wF[16], wG[16], wO[16];
    #pragma unroll
    for (int k = 0; k < 16; ++k) {
        const int m = (u - k) & 15;
        wI[k] = Whh[(u)      * 16 + m];
        wF[k] = Whh[(u + 16) * 16 + m];
        wG[k] = Whh[(u + 32) * 16 + m];
        wO[k] = Whh[(u + 48) * 16 + m];
    }
    const float wxI = Wih[u], wxF = Wih[u + 16], wxG = Wih[u + 32], wxO = Wih[u + 48];
    const float bI = bias[u], bF = bias[u + 16], bG = bias[u + 32], bO = bias[u + 48];

    // per-lane state: this lane's own h (unit u) and c
    float hn = h0[dir * (BATCH * HD) + b * HD + u];
    float c  = c0[dir * (BATCH * HD) + b * HD + u];

    const float* srow = sent + b * TLEN;
    float* obase = g_outBT + (size_t)b * TLEN * HID + dir * HD + u;

    // double-buffered x chunk (4 steps per chunk); bwd consumes reversed
    float4 xc = *(const float4*)(srow + (dir ? (TLEN - 4) : 0));
    for (int tb = 0; tb < TLEN; tb += 4) {
        float4 xn = xc;
        if (tb + 4 < TLEN)
            xn = *(const float4*)(srow + (dir ? (TLEN - 8 - tb) : (tb + 4)));
        float xa[4];
        if (dir) { xa[0] = xc.w; xa[1] = xc.z; xa[2] = xc.y; xa[3] = xc.x; }
        else     { xa[0] = xc.x; xa[1] = xc.y; xa[2] = xc.z; xa[3] = xc.w; }

        #pragma unroll
        for (int s2 = 0; s2 < 4; ++s2) {
            const int t   = tb + s2;
            const int pos = dir ? (TLEN - 1 - t) : t;
            const float x = xa[s2];

            float pi = fmaf(x, wxI, bI);
            float pf = fmaf(x, wxF, bF);
            float pg = fmaf(x, wxG, bG);
            float po = fmaf(x, wxO, bO);

            // rotate-fused dot: cur visits h[(u-k)&15] for k=0..15
            int cur = __float_as_int(hn);
            #pragma unroll
            for (int k = 0; k < 16; ++k) {
                const float hv = __int_as_float(cur);
                pi = fmaf(wI[k], hv, pi);
                pf = fmaf(wF[k], hv, pf);
                pg = fmaf(wG[k], hv, pg);
                po = fmaf(wO[k], hv, po);
                if (k < 15)
                    cur = __builtin_amdgcn_mov_dpp(cur, 0x121, 0xF, 0xF, true); // row_ror:1
            }

            const float ai = sigm_(pi), af = sigm_(pf), ao = sigm_(po);
            const float ag = tanh_(pg);
            c = fmaf(af, c, ai * ag);
            hn = ao * tanh_(c);

            obase[(size_t)pos * HID] = hn;
        }
        xc = xn;
    }
}

// ---------------------------------------------------------------------------
// K2: projections. Thread per (b,t). W1 etc. staged in LDS.
//   preA[b][t][h] = out[b,t,:] . W1[h,0:32]  + b1[h]
//   Ct  [b][h][t] = out[b,t,:] . W1[h,32:64]           (transposed for K34)
//   un  [b][t]    = out . Wu + bu
//   w2d [b][t]    = out . Wout
// ---------------------------------------------------------------------------
__global__ __launch_bounds__(256) void k2_proj(
    const float* __restrict__ W1,     // [32,64]
    const float* __restrict__ b1,     // [32]
    const float* __restrict__ Wu,     // [32]
    const float* __restrict__ bu,     // [1]
    const float* __restrict__ Wout)   // [32]
{
    __shared__ float w1s[HID * 64];
    __shared__ float b1s[HID], wus[HID], wos[HID];
    const int tid = threadIdx.x;
    for (int k = tid; k < HID * 64; k += 256) w1s[k] = W1[k];
    if (tid < HID) { b1s[tid] = b1[tid]; wus[tid] = Wu[tid]; wos[tid] = Wout[tid]; }
    __syncthreads();

    const int g = blockIdx.x * 256 + tid;    // 0..8191
    const int b = g >> 9;
    const int t = g & (TLEN - 1);

    float o[32];
    const float4* src = (const float4*)(g_outBT + (size_t)g * HID);
    #pragma unroll
    for (int qq = 0; qq < 8; ++qq) {
        float4 v = src[qq];
        o[qq * 4 + 0] = v.x; o[qq * 4 + 1] = v.y; o[qq * 4 + 2] = v.z; o[qq * 4 + 3] = v.w;
    }

    float* pa = g_preA + (size_t)g * HID;
    float* ct = g_Ct + (size_t)b * HID * TLEN + t;
    #pragma unroll 4
    for (int h = 0; h < HID; ++h) {
        float a = b1s[h], cacc = 0.f;
        const float* wr = &w1s[h * 64];
        #pragma unroll
        for (int k = 0; k < HID; ++k) {
            a    = fmaf(o[k], wr[k], a);
            cacc = fmaf(o[k], wr[32 + k], cacc);
        }
        pa[h] = a;
        ct[(size_t)h * TLEN] = cacc;
    }

    float ua = 0.f, wa = 0.f;
    #pragma unroll
    for (int k = 0; k < HID; ++k) { ua = fmaf(o[k], wus[k], ua); wa = fmaf(o[k], wos[k], wa); }
    g_un[g]  = ua + bu[0];
    g_w2d[g] = wa;
}

// ---------------------------------------------------------------------------
// K34: S[b,i] = sum_j sum_h relu(preA[b,i,h] + Ct[b,h,j]) * W2[h]
//      prob[b,i] = sigmoid((S - diag_i + 511*b2)/100 + un[b,i])
//      out[b] = sum_i prob[b,i]*w2d[b,i] / 512 + bout   (fused, O(1)-atomic tail)
// Block = (b, tile of 8 i's); 256 threads over j. Each tile adds its partial
// into g_accum[b] with ONE atomicAdd; the 64th arriver reads+resets via
// atomicExch and writes out[b].
// ---------------------------------------------------------------------------
__global__ __launch_bounds__(256) void k34_binary(
    const float* __restrict__ W2,     // [32]
    const float* __restrict__ b2p,    // [1]
    const float* __restrict__ boutp,  // [1]
    float* __restrict__ out)          // [16]
{
    const int b     = blockIdx.x >> 6;
    const int itile = blockIdx.x & 63;
    const int i0    = itile * 8;
    const int tid   = threadIdx.x;

    __shared__ float pa[8][HID];
    __shared__ float w2s[HID];
    __shared__ float redw[4][8];

    pa[tid >> 5][tid & 31] = g_preA[((size_t)b * TLEN + i0 + (tid >> 5)) * HID + (tid & 31)];
    if (tid < HID) w2s[tid] = W2[tid];
    __syncthreads();

    const float* ctb = g_Ct + (size_t)b * HID * TLEN;
    const int j0 = tid, j1 = tid + 256;

    float acc[8];
    #pragma unroll
    for (int ii = 0; ii < 8; ++ii) acc[ii] = 0.f;

    for (int h = 0; h < HID; ++h) {
        const float c0v = ctb[(size_t)h * TLEN + j0];
        const float c1v = ctb[(size_t)h * TLEN + j1];
        const float w   = w2s[h];
        #pragma unroll
        for (int ii = 0; ii < 8; ++ii) {
            const float p = pa[ii][h];
            acc[ii] = fmaf(fmaxf(p + c0v, 0.f), w, acc[ii]);
            acc[ii] = fmaf(fmaxf(p + c1v, 0.f), w, acc[ii]);
        }
    }

    #pragma unroll
    for (int ii = 0; ii < 8; ++ii) {
        float v = acc[ii];
        #pragma unroll
        for (int off = 32; off >= 1; off >>= 1) v += __shfl_down(v, off);
        if ((tid & 63) == 0) redw[tid >> 6][ii] = v;
    }
    __syncthreads();

    if (tid < 8) {
        const float S = redw[0][tid] + redw[1][tid] + redw[2][tid] + redw[3][tid];
        const int i = i0 + tid;
        float diag = 0.f;
        #pragma unroll
        for (int h = 0; h < HID; ++h)
            diag = fmaf(fmaxf(pa[tid][h] + ctb[(size_t)h * TLEN + i], 0.f), w2s[h], diag);
        const float b2 = b2p[0];
        const float s = (S - diag + (float)(TLEN - 1) * b2) * 0.01f + g_un[(size_t)b * TLEN + i];
        float contrib = sigm_(s) * g_w2d[(size_t)b * TLEN + i];
        // reduce 8 lanes (lanes 0..7 of wave 0)
        contrib += __shfl_down(contrib, 4);
        contrib += __shfl_down(contrib, 2);
        contrib += __shfl_down(contrib, 1);
        if (tid == 0) {
            atomicAdd(&g_accum[b], contrib);          // one device-scope atomic
            __threadfence();
            int old = atomicAdd(&g_cnt[b], 1);
            if (old == 63) {                          // last arriver for this b
                __threadfence();
                float tot = atomicExch(&g_accum[b], 0.0f);  // read + reset
                out[b] = tot * (1.0f / (float)TLEN) + boutp[0];
                atomicExch(&g_cnt[b], 0);             // restore for next call
            }
        }
    }
}

extern "C" void kernel_launch(void* const* d_in, const int* in_sizes, int n_in,
                              void* d_out, int out_size, void* d_ws, size_t ws_size,
                              hipStream_t stream) {
    const float* sent  = (const float*)d_in[0];
    const float* h0    = (const float*)d_in[1];
    const float* c0    = (const float*)d_in[2];
    const float* Wih_f = (const float*)d_in[3];
    const float* Whh_f = (const float*)d_in[4];
    const float* b_f   = (const float*)d_in[5];
    const float* Wih_b = (const float*)d_in[6];
    const float* Whh_b = (const float*)d_in[7];
    const float* b_b   = (const float*)d_in[8];
    const float* W1    = (const float*)d_in[9];
    const float* b1    = (const float*)d_in[10];
    const float* W2    = (const float*)d_in[11];
    const float* b2    = (const float*)d_in[12];
    const float* Wu    = (const float*)d_in[13];
    const float* bu    = (const float*)d_in[14];
    const float* Wout  = (const float*)d_in[15];
    const float* bout  = (const float*)d_in[16];

    k1_lstm<<<8, 64, 0, stream>>>(sent, h0, c0, Wih_f, Whh_f, b_f,
                                  Wih_b, Whh_b, b_b);
    k2_proj<<<32, 256, 0, stream>>>(W1, b1, Wu, bu, Wout);
    k34_binary<<<1024, 256, 0, stream>>>(W2, b2, bout, (float*)d_out);
}

// Round 7
// 281.153 us; speedup vs baseline: 1.1326x; 1.0965x over previous
//
#include <hip/hip_runtime.h>
#include <hip/hip_bf16.h>
#include <math.h>

// Sizes (fixed by the problem)
#define BATCH 16
#define TLEN  512
#define HD    16     // per-direction hidden
#define HID   32     // 2*HD

typedef float v2f __attribute__((ext_vector_type(2)));

// Static device scratch — avoids any assumption about ws_size.
// All arrays fully written before read each call; g_cnt/g_accum are zero-init
// .bss and restored to 0 by the last-arriver block each call.
__device__ float g_outBT[BATCH * TLEN * HID];   // 1 MB
__device__ float g_preA [BATCH * TLEN * HID];   // 1 MB
__device__ float g_Ct   [BATCH * HID * TLEN];   // 1 MB
__device__ float g_un   [BATCH * TLEN];
__device__ float g_w2d  [BATCH * TLEN];
__device__ float g_accum[BATCH];                // zero-initialized, self-resetting
__device__ int   g_cnt  [BATCH];                // zero-initialized, self-resetting

__device__ __forceinline__ float sigm_(float x) {
    return 1.0f / (1.0f + __expf(-x));
}
__device__ __forceinline__ float tanh_(float x) {
    float e = __expf(2.0f * x);
    return 1.0f - 2.0f / (e + 1.0f);
}

__device__ __forceinline__ v2f pk_fma(v2f a, v2f b, v2f c) {
#if __has_builtin(__builtin_elementwise_fma)
    return __builtin_elementwise_fma(a, b, c);   // -> v_pk_fma_f32
#else
    v2f r; r.x = fmaf(a.x, b.x, c.x); r.y = fmaf(a.y, b.y, c.y); return r;
#endif
}

// ---------------------------------------------------------------------------
// K1: bidirectional LSTM. 8 blocks x 64 threads; each wave carries 4 chains.
// Lane = (q = batch slot, u = unit). Recurrent h-distribution fused into the
// gate dots via a DPP row_ror:1 rotation chain (verified round 6). Weights
// are loaded through a VOLATILE pointer so the loads execute exactly once
// (round 6 showed VGPR=56 < 64 weights: the compiler was re-loading all
// weights from L1 every timestep — ~770 cyc/step). Gate pairs packed as
// float2 -> v_pk_fma_f32 halves fma issue.
// ---------------------------------------------------------------------------
__global__ __launch_bounds__(64, 1) void k1_lstm(
    const float* __restrict__ sent,   // [B,T]
    const float* __restrict__ h0,     // [2,B,16]
    const float* __restrict__ c0,     // [2,B,16]
    const float* __restrict__ Wih_f, const float* __restrict__ Whh_f, const float* __restrict__ b_f,
    const float* __restrict__ Wih_b, const float* __restrict__ Whh_b, const float* __restrict__ b_b)
{
    const int blk  = blockIdx.x;      // 0..7
    const int dir  = blk >> 2;        // 0 fwd, 1 bwd
    const int bg   = blk & 3;         // batch group of 4
    const int lane = threadIdx.x;
    const int q    = lane >> 4;       // batch slot in wave
    const int u    = lane & 15;       // hidden unit
    const int b    = bg * 4 + q;

    volatile const float* Wih  = dir ? Wih_b : Wih_f;
    volatile const float* Whh  = dir ? Whh_b : Whh_f;
    volatile const float* bias = dir ? b_b   : b_f;

    // Pre-rotated gate rows for unit u (torch order i,f,g,o at u,+16,+32,+48):
    // w*[k] multiplies h[(u-k)&15] (the value arriving after k row_ror:1 steps).
    // Packed: wIF = (i,f), wGO = (g,o). Volatile loads -> executed once, values
    // live in VGPRs across the whole t-loop.
    v2f wIF[16], wGO[16];
    #pragma unroll
    for (int k = 0; k < 16; ++k) {
        const int m = (u - k) & 15;
        v2f a, g2;
        a.x  = Whh[(u)      * 16 + m];
        a.y  = Whh[(u + 16) * 16 + m];
        g2.x = Whh[(u + 32) * 16 + m];
        g2.y = Whh[(u + 48) * 16 + m];
        wIF[k] = a;
        wGO[k] = g2;
    }
    const float wxI = Wih[u], wxF = Wih[u + 16], wxG = Wih[u + 32], wxO = Wih[u + 48];
    const float bI = bias[u], bF = bias[u + 16], bG = bias[u + 32], bO = bias[u + 48];

    // per-lane state: this lane's own h (unit u) and c
    float hn = h0[dir * (BATCH * HD) + b * HD + u];
    float c  = c0[dir * (BATCH * HD) + b * HD + u];

    const float* srow = sent + b * TLEN;
    float* obase = g_outBT + (size_t)b * TLEN * HID + dir * HD + u;

    // double-buffered x chunk (4 steps per chunk); bwd consumes reversed
    float4 xc = *(const float4*)(srow + (dir ? (TLEN - 4) : 0));
    for (int tb = 0; tb < TLEN; tb += 4) {
        float4 xn = xc;
        if (tb + 4 < TLEN)
            xn = *(const float4*)(srow + (dir ? (TLEN - 8 - tb) : (tb + 4)));
        float xa[4];
        if (dir) { xa[0] = xc.w; xa[1] = xc.z; xa[2] = xc.y; xa[3] = xc.x; }
        else     { xa[0] = xc.x; xa[1] = xc.y; xa[2] = xc.z; xa[3] = xc.w; }

        #pragma unroll
        for (int s2 = 0; s2 < 4; ++s2) {
            const int t   = tb + s2;
            const int pos = dir ? (TLEN - 1 - t) : t;
            const float x = xa[s2];

            v2f pIF, pGO;
            pIF.x = fmaf(x, wxI, bI);
            pIF.y = fmaf(x, wxF, bF);
            pGO.x = fmaf(x, wxG, bG);
            pGO.y = fmaf(x, wxO, bO);

            // rotate-fused dot: cur visits h[(u-k)&15] for k=0..15
            int cur = __float_as_int(hn);
            #pragma unroll
            for (int k = 0; k < 16; ++k) {
                const float hv = __int_as_float(cur);
                v2f hvv; hvv.x = hv; hvv.y = hv;
                pIF = pk_fma(wIF[k], hvv, pIF);
                pGO = pk_fma(wGO[k], hvv, pGO);
                if (k < 15)
                    cur = __builtin_amdgcn_mov_dpp(cur, 0x121, 0xF, 0xF, true); // row_ror:1
            }

            const float ai = sigm_(pIF.x), af = sigm_(pIF.y), ao = sigm_(pGO.y);
            const float ag = tanh_(pGO.x);
            c = fmaf(af, c, ai * ag);
            hn = ao * tanh_(c);

            obase[(size_t)pos * HID] = hn;
        }
        xc = xn;
    }
}

// ---------------------------------------------------------------------------
// K2: projections. Thread per (b,t). W1 etc. staged in LDS.
//   preA[b][t][h] = out[b,t,:] . W1[h,0:32]  + b1[h]
//   Ct  [b][h][t] = out[b,t,:] . W1[h,32:64]           (transposed for K34)
//   un  [b][t]    = out . Wu + bu
//   w2d [b][t]    = out . Wout
// ---------------------------------------------------------------------------
__global__ __launch_bounds__(256) void k2_proj(
    const float* __restrict__ W1,     // [32,64]
    const float* __restrict__ b1,     // [32]
    const float* __restrict__ Wu,     // [32]
    const float* __restrict__ bu,     // [1]
    const float* __restrict__ Wout)   // [32]
{
    __shared__ float w1s[HID * 64];
    __shared__ float b1s[HID], wus[HID], wos[HID];
    const int tid = threadIdx.x;
    for (int k = tid; k < HID * 64; k += 256) w1s[k] = W1[k];
    if (tid < HID) { b1s[tid] = b1[tid]; wus[tid] = Wu[tid]; wos[tid] = Wout[tid]; }
    __syncthreads();

    const int g = blockIdx.x * 256 + tid;    // 0..8191
    const int b = g >> 9;
    const int t = g & (TLEN - 1);

    float o[32];
    const float4* src = (const float4*)(g_outBT + (size_t)g * HID);
    #pragma unroll
    for (int qq = 0; qq < 8; ++qq) {
        float4 v = src[qq];
        o[qq * 4 + 0] = v.x; o[qq * 4 + 1] = v.y; o[qq * 4 + 2] = v.z; o[qq * 4 + 3] = v.w;
    }

    float* pa = g_preA + (size_t)g * HID;
    float* ct = g_Ct + (size_t)b * HID * TLEN + t;
    #pragma unroll 4
    for (int h = 0; h < HID; ++h) {
        float a = b1s[h], cacc = 0.f;
        const float* wr = &w1s[h * 64];
        #pragma unroll
        for (int k = 0; k < HID; ++k) {
            a    = fmaf(o[k], wr[k], a);
            cacc = fmaf(o[k], wr[32 + k], cacc);
        }
        pa[h] = a;
        ct[(size_t)h * TLEN] = cacc;
    }

    float ua = 0.f, wa = 0.f;
    #pragma unroll
    for (int k = 0; k < HID; ++k) { ua = fmaf(o[k], wus[k], ua); wa = fmaf(o[k], wos[k], wa); }
    g_un[g]  = ua + bu[0];
    g_w2d[g] = wa;
}

// ---------------------------------------------------------------------------
// K34: S[b,i] = sum_j sum_h relu(preA[b,i,h] + Ct[b,h,j]) * W2[h]
//      prob[b,i] = sigmoid((S - diag_i + 511*b2)/100 + un[b,i])
//      out[b] = sum_i prob[b,i]*w2d[b,i] / 512 + bout   (fused, O(1)-atomic tail)
// ---------------------------------------------------------------------------
__global__ __launch_bounds__(256) void k34_binary(
    const float* __restrict__ W2,     // [32]
    const float* __restrict__ b2p,    // [1]
    const float* __restrict__ boutp,  // [1]
    float* __restrict__ out)          // [16]
{
    const int b     = blockIdx.x >> 6;
    const int itile = blockIdx.x & 63;
    const int i0    = itile * 8;
    const int tid   = threadIdx.x;

    __shared__ float pa[8][HID];
    __shared__ float w2s[HID];
    __shared__ float redw[4][8];

    pa[tid >> 5][tid & 31] = g_preA[((size_t)b * TLEN + i0 + (tid >> 5)) * HID + (tid & 31)];
    if (tid < HID) w2s[tid] = W2[tid];
    __syncthreads();

    const float* ctb = g_Ct + (size_t)b * HID * TLEN;
    const int j0 = tid, j1 = tid + 256;

    float acc[8];
    #pragma unroll
    for (int ii = 0; ii < 8; ++ii) acc[ii] = 0.f;

    for (int h = 0; h < HID; ++h) {
        const float c0v = ctb[(size_t)h * TLEN + j0];
        const float c1v = ctb[(size_t)h * TLEN + j1];
        const float w   = w2s[h];
        #pragma unroll
        for (int ii = 0; ii < 8; ++ii) {
            const float p = pa[ii][h];
            acc[ii] = fmaf(fmaxf(p + c0v, 0.f), w, acc[ii]);
            acc[ii] = fmaf(fmaxf(p + c1v, 0.f), w, acc[ii]);
        }
    }

    #pragma unroll
    for (int ii = 0; ii < 8; ++ii) {
        float v = acc[ii];
        #pragma unroll
        for (int off = 32; off >= 1; off >>= 1) v += __shfl_down(v, off);
        if ((tid & 63) == 0) redw[tid >> 6][ii] = v;
    }
    __syncthreads();

    if (tid < 8) {
        const float S = redw[0][tid] + redw[1][tid] + redw[2][tid] + redw[3][tid];
        const int i = i0 + tid;
        float diag = 0.f;
        #pragma unroll
        for (int h = 0; h < HID; ++h)
            diag = fmaf(fmaxf(pa[tid][h] + ctb[(size_t)h * TLEN + i], 0.f), w2s[h], diag);
        const float b2 = b2p[0];
        const float s = (S - diag + (float)(TLEN - 1) * b2) * 0.01f + g_un[(size_t)b * TLEN + i];
        float contrib = sigm_(s) * g_w2d[(size_t)b * TLEN + i];
        // reduce 8 lanes (lanes 0..7 of wave 0)
        contrib += __shfl_down(contrib, 4);
        contrib += __shfl_down(contrib, 2);
        contrib += __shfl_down(contrib, 1);
        if (tid == 0) {
            atomicAdd(&g_accum[b], contrib);          // one device-scope atomic
            __threadfence();
            int old = atomicAdd(&g_cnt[b], 1);
            if (old == 63) {                          // last arriver for this b
                __threadfence();
                float tot = atomicExch(&g_accum[b], 0.0f);  // read + reset
                out[b] = tot * (1.0f / (float)TLEN) + boutp[0];
                atomicExch(&g_cnt[b], 0);             // restore for next call
            }
        }
    }
}

extern "C" void kernel_launch(void* const* d_in, const int* in_sizes, int n_in,
                              void* d_out, int out_size, void* d_ws, size_t ws_size,
                              hipStream_t stream) {
    const float* sent  = (const float*)d_in[0];
    const float* h0    = (const float*)d_in[1];
    const float* c0    = (const float*)d_in[2];
    const float* Wih_f = (const float*)d_in[3];
    const float* Whh_f = (const float*)d_in[4];
    const float* b_f   = (const float*)d_in[5];
    const float* Wih_b = (const float*)d_in[6];
    const float* Whh_b = (const float*)d_in[7];
    const float* b_b   = (const float*)d_in[8];
    const float* W1    = (const float*)d_in[9];
    const float* b1    = (const float*)d_in[10];
    const float* W2    = (const float*)d_in[11];
    const float* b2    = (const float*)d_in[12];
    const float* Wu    = (const float*)d_in[13];
    const float* bu    = (const float*)d_in[14];
    const float* Wout  = (const float*)d_in[15];
    const float* bout  = (const float*)d_in[16];

    k1_lstm<<<8, 64, 0, stream>>>(sent, h0, c0, Wih_f, Whh_f, b_f,
                                  Wih_b, Whh_b, b_b);
    k2_proj<<<32, 256, 0, stream>>>(W1, b1, Wu, bu, Wout);
    k34_binary<<<1024, 256, 0, stream>>>(W2, b2, bout, (float*)d_out);
}